// Round 1
// baseline (2137.399 us; speedup 1.0000x reference)
//
#include <hip/hip_runtime.h>

typedef __attribute__((ext_vector_type(8))) short short8;
typedef __attribute__((ext_vector_type(4))) float f32x4;

#define NN 100000
#define NE 600000
#define RR 128
#define HH 256
#define AP 392   // edge A-tile LDS row stride (384 + 8 pad)
#define HP 264   // H / node A-tile LDS row stride (256 + 8 pad)

__device__ __forceinline__ unsigned short f2bf(float f) {
    unsigned u = __builtin_bit_cast(unsigned, f);
    u = (u + 0x7fffu + ((u >> 16) & 1u)) >> 16;   // RNE
    return (unsigned short)u;
}

__global__ __launch_bounds__(256) void transpose_cast(const float* __restrict__ src,
                                                      unsigned short* __restrict__ dst,
                                                      int K, int C) {
    int i = blockIdx.x * 256 + threadIdx.x;
    if (i >= K * C) return;
    int c = i / K, k = i - c * K;
    dst[i] = f2bf(src[k * C + c]);   // dst[c][k] = src[k][c]
}

// ---------------- edge kernel: gather + MLP + scatter-add ----------------
__global__ __launch_bounds__(256) void edge_kernel(
    const float* __restrict__ node_rep, const float* __restrict__ edge_attr,
    const int* __restrict__ esrc, const int* __restrict__ edst,
    const unsigned short* __restrict__ w1t, const float* __restrict__ b1,
    const unsigned short* __restrict__ w2t, const float* __restrict__ b2,
    float* __restrict__ edge_out, float* __restrict__ e2n)
{
    __shared__ unsigned short Abuf[64 * AP];   // A-tile, later reused as H-tile
    __shared__ int sidx[64], didx[64];
    const int tid = threadIdx.x;
    const int e0 = blockIdx.x * 64;

    if (tid < 64) sidx[tid] = esrc[e0 + tid];
    else if (tid < 128) didx[tid - 64] = edst[e0 + tid - 64];
    __syncthreads();

    // gather [edge_attr | node_src | node_dst] -> bf16 LDS, 64 rows x 384
    for (int i = tid; i < 64 * 96; i += 256) {
        int row = i / 96;
        int c4 = i - row * 96;
        const float* p;
        if (c4 < 32)      p = edge_attr + (size_t)(e0 + row) * RR + (c4 << 2);
        else if (c4 < 64) p = node_rep + (size_t)sidx[row] * RR + ((c4 - 32) << 2);
        else              p = node_rep + (size_t)didx[row] * RR + ((c4 - 64) << 2);
        float4 v = *reinterpret_cast<const float4*>(p);
        uint2 u;
        u.x = f2bf(v.x) | ((unsigned)f2bf(v.y) << 16);
        u.y = f2bf(v.z) | ((unsigned)f2bf(v.w) << 16);
        *reinterpret_cast<uint2*>(&Abuf[row * AP + (c4 << 2)]) = u;
    }
    __syncthreads();

    const int lane = tid & 63, wave = tid >> 6;
    const int l15 = lane & 15, l4 = lane >> 4;
    const int hbase = wave * 64;

    // GEMM1': D'[h][e] = sum_k W1T[h][k] * A[e][k]   (h = hidden, e = edge)
    f32x4 acc[4][4] = {};
    for (int kk = 0; kk < 384; kk += 32) {
        const int koff = kk + l4 * 8;
        short8 bfr[4];
        #pragma unroll
        for (int et = 0; et < 4; ++et)
            bfr[et] = *reinterpret_cast<const short8*>(&Abuf[(et * 16 + l15) * AP + koff]);
        #pragma unroll
        for (int ht = 0; ht < 4; ++ht) {
            short8 afr = *reinterpret_cast<const short8*>(w1t + (size_t)(hbase + ht * 16 + l15) * 384 + koff);
            #pragma unroll
            for (int et = 0; et < 4; ++et)
                acc[ht][et] = __builtin_amdgcn_mfma_f32_16x16x32_bf16(afr, bfr[et], acc[ht][et], 0, 0, 0);
        }
    }
    __syncthreads();   // everyone done reading Abuf

    // bias + relu + bf16, store H[e][h] into reused LDS (stride HP)
    unsigned short* Hbuf = Abuf;
    #pragma unroll
    for (int ht = 0; ht < 4; ++ht) {
        const int h0 = hbase + ht * 16 + l4 * 4;
        float4 bb = *reinterpret_cast<const float4*>(b1 + h0);
        #pragma unroll
        for (int et = 0; et < 4; ++et) {
            int e = et * 16 + l15;
            float x0 = fmaxf(acc[ht][et][0] + bb.x, 0.f);
            float x1 = fmaxf(acc[ht][et][1] + bb.y, 0.f);
            float x2 = fmaxf(acc[ht][et][2] + bb.z, 0.f);
            float x3 = fmaxf(acc[ht][et][3] + bb.w, 0.f);
            uint2 u;
            u.x = f2bf(x0) | ((unsigned)f2bf(x1) << 16);
            u.y = f2bf(x2) | ((unsigned)f2bf(x3) << 16);
            *reinterpret_cast<uint2*>(&Hbuf[e * HP + h0]) = u;
        }
    }
    __syncthreads();

    // GEMM2': D2'[c][e] = sum_h W2T[c][h] * H[e][h]
    f32x4 acc2[2][4] = {};
    const int cbase = wave * 32;
    for (int kk = 0; kk < 256; kk += 32) {
        const int koff = kk + l4 * 8;
        short8 bfr[4];
        #pragma unroll
        for (int et = 0; et < 4; ++et)
            bfr[et] = *reinterpret_cast<const short8*>(&Hbuf[(et * 16 + l15) * HP + koff]);
        #pragma unroll
        for (int ct = 0; ct < 2; ++ct) {
            short8 afr = *reinterpret_cast<const short8*>(w2t + (size_t)(cbase + ct * 16 + l15) * 256 + koff);
            #pragma unroll
            for (int et = 0; et < 4; ++et)
                acc2[ct][et] = __builtin_amdgcn_mfma_f32_16x16x32_bf16(afr, bfr[et], acc2[ct][et], 0, 0, 0);
        }
    }

    // epilogue: bias, store edge_out, scatter-add to both endpoints
    #pragma unroll
    for (int ct = 0; ct < 2; ++ct) {
        const int c0 = cbase + ct * 16 + l4 * 4;
        float4 bb = *reinterpret_cast<const float4*>(b2 + c0);
        #pragma unroll
        for (int et = 0; et < 4; ++et) {
            int e = et * 16 + l15;
            float4 v;
            v.x = acc2[ct][et][0] + bb.x;
            v.y = acc2[ct][et][1] + bb.y;
            v.z = acc2[ct][et][2] + bb.z;
            v.w = acc2[ct][et][3] + bb.w;
            *reinterpret_cast<float4*>(edge_out + (size_t)(e0 + e) * RR + c0) = v;
            float* ps = e2n + (size_t)sidx[e] * RR + c0;
            atomicAdd(ps + 0, v.x); atomicAdd(ps + 1, v.y);
            atomicAdd(ps + 2, v.z); atomicAdd(ps + 3, v.w);
            float* pd = e2n + (size_t)didx[e] * RR + c0;
            atomicAdd(pd + 0, v.x); atomicAdd(pd + 1, v.y);
            atomicAdd(pd + 2, v.z); atomicAdd(pd + 3, v.w);
        }
    }
}

// ---------------- node kernel: [node_rep | e2n] MLP -> node_out ----------------
__global__ __launch_bounds__(256) void node_kernel(
    const float* __restrict__ node_rep,
    const unsigned short* __restrict__ w1t, const float* __restrict__ b1,
    const unsigned short* __restrict__ w2t, const float* __restrict__ b2,
    float* __restrict__ out)   // out == e2n region; read rows then overwrite
{
    __shared__ unsigned short Abuf[64 * HP];
    const int tid = threadIdx.x;
    const int n0 = blockIdx.x * 64;

    for (int i = tid; i < 64 * 64; i += 256) {
        int row = i >> 6;
        int c4 = i & 63;
        int n = n0 + row; if (n >= NN) n = NN - 1;
        const float* p = (c4 < 32) ? node_rep + (size_t)n * RR + (c4 << 2)
                                   : out + (size_t)n * RR + ((c4 - 32) << 2);
        float4 v = *reinterpret_cast<const float4*>(p);
        uint2 u;
        u.x = f2bf(v.x) | ((unsigned)f2bf(v.y) << 16);
        u.y = f2bf(v.z) | ((unsigned)f2bf(v.w) << 16);
        *reinterpret_cast<uint2*>(&Abuf[row * HP + (c4 << 2)]) = u;
    }
    __syncthreads();

    const int lane = tid & 63, wave = tid >> 6;
    const int l15 = lane & 15, l4 = lane >> 4;
    const int hbase = wave * 64;

    f32x4 acc[4][4] = {};
    for (int kk = 0; kk < 256; kk += 32) {
        const int koff = kk + l4 * 8;
        short8 bfr[4];
        #pragma unroll
        for (int et = 0; et < 4; ++et)
            bfr[et] = *reinterpret_cast<const short8*>(&Abuf[(et * 16 + l15) * HP + koff]);
        #pragma unroll
        for (int ht = 0; ht < 4; ++ht) {
            short8 afr = *reinterpret_cast<const short8*>(w1t + (size_t)(hbase + ht * 16 + l15) * 256 + koff);
            #pragma unroll
            for (int et = 0; et < 4; ++et)
                acc[ht][et] = __builtin_amdgcn_mfma_f32_16x16x32_bf16(afr, bfr[et], acc[ht][et], 0, 0, 0);
        }
    }
    __syncthreads();

    unsigned short* Hbuf = Abuf;
    #pragma unroll
    for (int ht = 0; ht < 4; ++ht) {
        const int h0 = hbase + ht * 16 + l4 * 4;
        float4 bb = *reinterpret_cast<const float4*>(b1 + h0);
        #pragma unroll
        for (int et = 0; et < 4; ++et) {
            int e = et * 16 + l15;
            float x0 = fmaxf(acc[ht][et][0] + bb.x, 0.f);
            float x1 = fmaxf(acc[ht][et][1] + bb.y, 0.f);
            float x2 = fmaxf(acc[ht][et][2] + bb.z, 0.f);
            float x3 = fmaxf(acc[ht][et][3] + bb.w, 0.f);
            uint2 u;
            u.x = f2bf(x0) | ((unsigned)f2bf(x1) << 16);
            u.y = f2bf(x2) | ((unsigned)f2bf(x3) << 16);
            *reinterpret_cast<uint2*>(&Hbuf[e * HP + h0]) = u;
        }
    }
    __syncthreads();

    f32x4 acc2[2][4] = {};
    const int cbase = wave * 32;
    for (int kk = 0; kk < 256; kk += 32) {
        const int koff = kk + l4 * 8;
        short8 bfr[4];
        #pragma unroll
        for (int et = 0; et < 4; ++et)
            bfr[et] = *reinterpret_cast<const short8*>(&Hbuf[(et * 16 + l15) * HP + koff]);
        #pragma unroll
        for (int ct = 0; ct < 2; ++ct) {
            short8 afr = *reinterpret_cast<const short8*>(w2t + (size_t)(cbase + ct * 16 + l15) * 256 + koff);
            #pragma unroll
            for (int et = 0; et < 4; ++et)
                acc2[ct][et] = __builtin_amdgcn_mfma_f32_16x16x32_bf16(afr, bfr[et], acc2[ct][et], 0, 0, 0);
        }
    }

    #pragma unroll
    for (int ct = 0; ct < 2; ++ct) {
        const int c0 = cbase + ct * 16 + l4 * 4;
        float4 bb = *reinterpret_cast<const float4*>(b2 + c0);
        #pragma unroll
        for (int et = 0; et < 4; ++et) {
            int n = n0 + et * 16 + l15;
            if (n < NN) {
                float4 v;
                v.x = acc2[ct][et][0] + bb.x;
                v.y = acc2[ct][et][1] + bb.y;
                v.z = acc2[ct][et][2] + bb.z;
                v.w = acc2[ct][et][3] + bb.w;
                *reinterpret_cast<float4*>(out + (size_t)n * RR + c0) = v;
            }
        }
    }
}

extern "C" void kernel_launch(void* const* d_in, const int* in_sizes, int n_in,
                              void* d_out, int out_size, void* d_ws, size_t ws_size,
                              hipStream_t stream) {
    const float* node_rep  = (const float*)d_in[0];
    const float* edge_attr = (const float*)d_in[1];
    const int*   esrc      = (const int*)d_in[2];
    const int*   edst      = (const int*)d_in[3];
    const float* W1e = (const float*)d_in[4];
    const float* b1e = (const float*)d_in[5];
    const float* W2e = (const float*)d_in[6];
    const float* b2e = (const float*)d_in[7];
    const float* W1n = (const float*)d_in[8];
    const float* b1n = (const float*)d_in[9];
    const float* W2n = (const float*)d_in[10];
    const float* b2n = (const float*)d_in[11];

    float* out      = (float*)d_out;
    float* node_out = out;                          // N*R, doubles as e2n accumulator
    float* edge_out = out + (size_t)NN * RR;        // E*R

    unsigned short* w1et = (unsigned short*)d_ws;   // [256][384]
    unsigned short* w2et = w1et + 256 * 384;        // [128][256]
    unsigned short* w1nt = w2et + 128 * 256;        // [256][256]
    unsigned short* w2nt = w1nt + 256 * 256;        // [128][256]

    hipMemsetAsync(node_out, 0, (size_t)NN * RR * sizeof(float), stream);

    transpose_cast<<<(384 * 256 + 255) / 256, 256, 0, stream>>>(W1e, w1et, 384, 256);
    transpose_cast<<<(256 * 128 + 255) / 256, 256, 0, stream>>>(W2e, w2et, 256, 128);
    transpose_cast<<<(256 * 256 + 255) / 256, 256, 0, stream>>>(W1n, w1nt, 256, 256);
    transpose_cast<<<(256 * 128 + 255) / 256, 256, 0, stream>>>(W2n, w2nt, 256, 128);

    edge_kernel<<<NE / 64, 256, 0, stream>>>(node_rep, edge_attr, esrc, edst,
                                             w1et, b1e, w2et, b2e,
                                             edge_out, node_out);

    node_kernel<<<(NN + 63) / 64, 256, 0, stream>>>(node_rep,
                                                    w1nt, b1n, w2nt, b2n,
                                                    node_out);
}

// Round 2
// 1001.565 us; speedup vs baseline: 2.1341x; 2.1341x over previous
//
#include <hip/hip_runtime.h>

typedef __attribute__((ext_vector_type(8))) short short8;
typedef __attribute__((ext_vector_type(4))) float f32x4;

#define NN 100000
#define NE 600000
#define RR 128
#define HH 256
#define AP 392   // edge A-tile LDS row stride (384 + 8 pad)
#define HP 264   // H / node A-tile LDS row stride (256 + 8 pad)

__device__ __forceinline__ unsigned short f2bf(float f) {
    unsigned u = __builtin_bit_cast(unsigned, f);
    u = (u + 0x7fffu + ((u >> 16) & 1u)) >> 16;   // RNE
    return (unsigned short)u;
}

__global__ __launch_bounds__(256) void transpose_cast(const float* __restrict__ src,
                                                      unsigned short* __restrict__ dst,
                                                      int K, int C) {
    int i = blockIdx.x * 256 + threadIdx.x;
    if (i >= K * C) return;
    int c = i / K, k = i - c * K;
    dst[i] = f2bf(src[k * C + c]);   // dst[c][k] = src[k][c]
}

// ---------------- CSR build ----------------
__global__ __launch_bounds__(256) void count_kernel(const int* __restrict__ esrc,
                                                    const int* __restrict__ edst,
                                                    int* __restrict__ cnt) {
    int i = blockIdx.x * 256 + threadIdx.x;
    if (i < NE) {
        atomicAdd(&cnt[esrc[i]], 1);
        atomicAdd(&cnt[edst[i]], 1);
    }
}

// single-workgroup exclusive scan: offs[i] = sum(cnt[0..i)), i in [0, NN];
// also rewrites cnt[i] = offs[i] (fill cursor).
__global__ __launch_bounds__(1024) void scan_kernel(int* __restrict__ cnt,
                                                    int* __restrict__ offs) {
    __shared__ int woff[16];
    __shared__ int carry_s;
    const int tid = threadIdx.x;
    const int lane = tid & 63, w = tid >> 6;
    if (tid == 0) carry_s = 0;
    __syncthreads();
    for (int base = 0; base <= NN; base += 1024) {
        int i = base + tid;
        int v = (i < NN) ? cnt[i] : 0;
        int s = v;
        #pragma unroll
        for (int d = 1; d < 64; d <<= 1) {
            int t = __shfl_up(s, d, 64);
            if (lane >= d) s += t;
        }
        if (lane == 63) woff[w] = s;
        __syncthreads();
        if (tid == 0) {
            int run = carry_s;
            #pragma unroll
            for (int k = 0; k < 16; ++k) { int t = woff[k]; woff[k] = run; run += t; }
            carry_s = run;
        }
        __syncthreads();
        int excl = woff[w] + (s - v);
        if (i <= NN) offs[i] = excl;
        if (i < NN) cnt[i] = excl;
        __syncthreads();
    }
}

__global__ __launch_bounds__(256) void fill_kernel(const int* __restrict__ esrc,
                                                   const int* __restrict__ edst,
                                                   int* __restrict__ cur,
                                                   int* __restrict__ adj) {
    int i = blockIdx.x * 256 + threadIdx.x;
    if (i < NE) {
        int p = atomicAdd(&cur[esrc[i]], 1);
        adj[p] = i;
        int q = atomicAdd(&cur[edst[i]], 1);
        adj[q] = i;
    }
}

// ---------------- edge kernel: gather + MLP -> edge_out ----------------
__global__ __launch_bounds__(256) void edge_kernel(
    const float* __restrict__ node_rep, const float* __restrict__ edge_attr,
    const int* __restrict__ esrc, const int* __restrict__ edst,
    const unsigned short* __restrict__ w1t, const float* __restrict__ b1,
    const unsigned short* __restrict__ w2t, const float* __restrict__ b2,
    float* __restrict__ edge_out)
{
    __shared__ unsigned short Abuf[64 * AP];   // A-tile, later reused as H-tile
    __shared__ int sidx[64], didx[64];
    const int tid = threadIdx.x;
    const int e0 = blockIdx.x * 64;

    if (tid < 64) sidx[tid] = esrc[e0 + tid];
    else if (tid < 128) didx[tid - 64] = edst[e0 + tid - 64];
    __syncthreads();

    // gather [edge_attr | node_src | node_dst] -> bf16 LDS, 64 rows x 384
    for (int i = tid; i < 64 * 96; i += 256) {
        int row = i / 96;
        int c4 = i - row * 96;
        const float* p;
        if (c4 < 32)      p = edge_attr + (size_t)(e0 + row) * RR + (c4 << 2);
        else if (c4 < 64) p = node_rep + (size_t)sidx[row] * RR + ((c4 - 32) << 2);
        else              p = node_rep + (size_t)didx[row] * RR + ((c4 - 64) << 2);
        float4 v = *reinterpret_cast<const float4*>(p);
        uint2 u;
        u.x = f2bf(v.x) | ((unsigned)f2bf(v.y) << 16);
        u.y = f2bf(v.z) | ((unsigned)f2bf(v.w) << 16);
        *reinterpret_cast<uint2*>(&Abuf[row * AP + (c4 << 2)]) = u;
    }
    __syncthreads();

    const int lane = tid & 63, wave = tid >> 6;
    const int l15 = lane & 15, l4 = lane >> 4;
    const int hbase = wave * 64;

    // GEMM1': D'[h][e] = sum_k W1T[h][k] * A[e][k]
    f32x4 acc[4][4] = {};
    for (int kk = 0; kk < 384; kk += 32) {
        const int koff = kk + l4 * 8;
        short8 bfr[4];
        #pragma unroll
        for (int et = 0; et < 4; ++et)
            bfr[et] = *reinterpret_cast<const short8*>(&Abuf[(et * 16 + l15) * AP + koff]);
        #pragma unroll
        for (int ht = 0; ht < 4; ++ht) {
            short8 afr = *reinterpret_cast<const short8*>(w1t + (size_t)(hbase + ht * 16 + l15) * 384 + koff);
            #pragma unroll
            for (int et = 0; et < 4; ++et)
                acc[ht][et] = __builtin_amdgcn_mfma_f32_16x16x32_bf16(afr, bfr[et], acc[ht][et], 0, 0, 0);
        }
    }
    __syncthreads();

    // bias + relu + bf16, store H[e][h] into reused LDS (stride HP)
    unsigned short* Hbuf = Abuf;
    #pragma unroll
    for (int ht = 0; ht < 4; ++ht) {
        const int h0 = hbase + ht * 16 + l4 * 4;
        float4 bb = *reinterpret_cast<const float4*>(b1 + h0);
        #pragma unroll
        for (int et = 0; et < 4; ++et) {
            int e = et * 16 + l15;
            float x0 = fmaxf(acc[ht][et][0] + bb.x, 0.f);
            float x1 = fmaxf(acc[ht][et][1] + bb.y, 0.f);
            float x2 = fmaxf(acc[ht][et][2] + bb.z, 0.f);
            float x3 = fmaxf(acc[ht][et][3] + bb.w, 0.f);
            uint2 u;
            u.x = f2bf(x0) | ((unsigned)f2bf(x1) << 16);
            u.y = f2bf(x2) | ((unsigned)f2bf(x3) << 16);
            *reinterpret_cast<uint2*>(&Hbuf[e * HP + h0]) = u;
        }
    }
    __syncthreads();

    // GEMM2': D2'[c][e] = sum_h W2T[c][h] * H[e][h]
    f32x4 acc2[2][4] = {};
    const int cbase = wave * 32;
    for (int kk = 0; kk < 256; kk += 32) {
        const int koff = kk + l4 * 8;
        short8 bfr[4];
        #pragma unroll
        for (int et = 0; et < 4; ++et)
            bfr[et] = *reinterpret_cast<const short8*>(&Hbuf[(et * 16 + l15) * HP + koff]);
        #pragma unroll
        for (int ct = 0; ct < 2; ++ct) {
            short8 afr = *reinterpret_cast<const short8*>(w2t + (size_t)(cbase + ct * 16 + l15) * 256 + koff);
            #pragma unroll
            for (int et = 0; et < 4; ++et)
                acc2[ct][et] = __builtin_amdgcn_mfma_f32_16x16x32_bf16(afr, bfr[et], acc2[ct][et], 0, 0, 0);
        }
    }

    // epilogue: bias + store edge_out (no atomics)
    #pragma unroll
    for (int ct = 0; ct < 2; ++ct) {
        const int c0 = cbase + ct * 16 + l4 * 4;
        float4 bb = *reinterpret_cast<const float4*>(b2 + c0);
        #pragma unroll
        for (int et = 0; et < 4; ++et) {
            int e = et * 16 + l15;
            float4 v;
            v.x = acc2[ct][et][0] + bb.x;
            v.y = acc2[ct][et][1] + bb.y;
            v.z = acc2[ct][et][2] + bb.z;
            v.w = acc2[ct][et][3] + bb.w;
            *reinterpret_cast<float4*>(edge_out + (size_t)(e0 + e) * RR + c0) = v;
        }
    }
}

// ---------------- node kernel: pull e2n via CSR + MLP -> node_out ----------------
__global__ __launch_bounds__(256) void node_kernel(
    const float* __restrict__ node_rep,
    const int* __restrict__ offs, const int* __restrict__ adj,
    const float* __restrict__ edge_out,
    const unsigned short* __restrict__ w1t, const float* __restrict__ b1,
    const unsigned short* __restrict__ w2t, const float* __restrict__ b2,
    float* __restrict__ out)
{
    __shared__ unsigned short Abuf[64 * HP];
    const int tid = threadIdx.x;
    const int n0 = blockIdx.x * 64;
    const int r = tid >> 2, q = tid & 3;       // row, quarter (32 floats each)
    const int n = n0 + r;

    // node_rep -> Abuf cols [q*32, q*32+32)
    {
        int nc = n < NN ? n : NN - 1;
        const f32x4* src = reinterpret_cast<const f32x4*>(node_rep + (size_t)nc * RR + q * 32);
        #pragma unroll
        for (int j = 0; j < 8; ++j) {
            f32x4 v = src[j];
            uint2 u;
            u.x = f2bf(v[0]) | ((unsigned)f2bf(v[1]) << 16);
            u.y = f2bf(v[2]) | ((unsigned)f2bf(v[3]) << 16);
            *reinterpret_cast<uint2*>(&Abuf[r * HP + q * 32 + (j << 2)]) = u;
        }
    }
    // e2n: f32 gather-sum of incident edge_out rows -> Abuf cols [128+q*32, ...)
    {
        f32x4 acc8[8] = {};
        if (n < NN) {
            const int pe = offs[n + 1];
            for (int p = offs[n]; p < pe; ++p) {
                int e = adj[p];
                const f32x4* src = reinterpret_cast<const f32x4*>(edge_out + (size_t)e * RR + q * 32);
                #pragma unroll
                for (int j = 0; j < 8; ++j) acc8[j] += src[j];
            }
        }
        #pragma unroll
        for (int j = 0; j < 8; ++j) {
            uint2 u;
            u.x = f2bf(acc8[j][0]) | ((unsigned)f2bf(acc8[j][1]) << 16);
            u.y = f2bf(acc8[j][2]) | ((unsigned)f2bf(acc8[j][3]) << 16);
            *reinterpret_cast<uint2*>(&Abuf[r * HP + 128 + q * 32 + (j << 2)]) = u;
        }
    }
    __syncthreads();

    const int lane = tid & 63, wave = tid >> 6;
    const int l15 = lane & 15, l4 = lane >> 4;
    const int hbase = wave * 64;

    f32x4 acc[4][4] = {};
    for (int kk = 0; kk < 256; kk += 32) {
        const int koff = kk + l4 * 8;
        short8 bfr[4];
        #pragma unroll
        for (int et = 0; et < 4; ++et)
            bfr[et] = *reinterpret_cast<const short8*>(&Abuf[(et * 16 + l15) * HP + koff]);
        #pragma unroll
        for (int ht = 0; ht < 4; ++ht) {
            short8 afr = *reinterpret_cast<const short8*>(w1t + (size_t)(hbase + ht * 16 + l15) * 256 + koff);
            #pragma unroll
            for (int et = 0; et < 4; ++et)
                acc[ht][et] = __builtin_amdgcn_mfma_f32_16x16x32_bf16(afr, bfr[et], acc[ht][et], 0, 0, 0);
        }
    }
    __syncthreads();

    unsigned short* Hbuf = Abuf;
    #pragma unroll
    for (int ht = 0; ht < 4; ++ht) {
        const int h0 = hbase + ht * 16 + l4 * 4;
        float4 bb = *reinterpret_cast<const float4*>(b1 + h0);
        #pragma unroll
        for (int et = 0; et < 4; ++et) {
            int e = et * 16 + l15;
            float x0 = fmaxf(acc[ht][et][0] + bb.x, 0.f);
            float x1 = fmaxf(acc[ht][et][1] + bb.y, 0.f);
            float x2 = fmaxf(acc[ht][et][2] + bb.z, 0.f);
            float x3 = fmaxf(acc[ht][et][3] + bb.w, 0.f);
            uint2 u;
            u.x = f2bf(x0) | ((unsigned)f2bf(x1) << 16);
            u.y = f2bf(x2) | ((unsigned)f2bf(x3) << 16);
            *reinterpret_cast<uint2*>(&Hbuf[e * HP + h0]) = u;
        }
    }
    __syncthreads();

    f32x4 acc2[2][4] = {};
    const int cbase = wave * 32;
    for (int kk = 0; kk < 256; kk += 32) {
        const int koff = kk + l4 * 8;
        short8 bfr[4];
        #pragma unroll
        for (int et = 0; et < 4; ++et)
            bfr[et] = *reinterpret_cast<const short8*>(&Hbuf[(et * 16 + l15) * HP + koff]);
        #pragma unroll
        for (int ct = 0; ct < 2; ++ct) {
            short8 afr = *reinterpret_cast<const short8*>(w2t + (size_t)(cbase + ct * 16 + l15) * 256 + koff);
            #pragma unroll
            for (int et = 0; et < 4; ++et)
                acc2[ct][et] = __builtin_amdgcn_mfma_f32_16x16x32_bf16(afr, bfr[et], acc2[ct][et], 0, 0, 0);
        }
    }

    #pragma unroll
    for (int ct = 0; ct < 2; ++ct) {
        const int c0 = cbase + ct * 16 + l4 * 4;
        float4 bb = *reinterpret_cast<const float4*>(b2 + c0);
        #pragma unroll
        for (int et = 0; et < 4; ++et) {
            int nn = n0 + et * 16 + l15;
            if (nn < NN) {
                float4 v;
                v.x = acc2[ct][et][0] + bb.x;
                v.y = acc2[ct][et][1] + bb.y;
                v.z = acc2[ct][et][2] + bb.z;
                v.w = acc2[ct][et][3] + bb.w;
                *reinterpret_cast<float4*>(out + (size_t)nn * RR + c0) = v;
            }
        }
    }
}

extern "C" void kernel_launch(void* const* d_in, const int* in_sizes, int n_in,
                              void* d_out, int out_size, void* d_ws, size_t ws_size,
                              hipStream_t stream) {
    const float* node_rep  = (const float*)d_in[0];
    const float* edge_attr = (const float*)d_in[1];
    const int*   esrc      = (const int*)d_in[2];
    const int*   edst      = (const int*)d_in[3];
    const float* W1e = (const float*)d_in[4];
    const float* b1e = (const float*)d_in[5];
    const float* W2e = (const float*)d_in[6];
    const float* b2e = (const float*)d_in[7];
    const float* W1n = (const float*)d_in[8];
    const float* b1n = (const float*)d_in[9];
    const float* W2n = (const float*)d_in[10];
    const float* b2n = (const float*)d_in[11];

    float* out      = (float*)d_out;
    float* node_out = out;                          // N*R
    float* edge_out = out + (size_t)NN * RR;        // E*R

    // workspace layout
    char* ws = (char*)d_ws;
    unsigned short* w1et = (unsigned short*)ws;                 // [256][384]
    unsigned short* w2et = w1et + 256 * 384;                    // [128][256]
    unsigned short* w1nt = w2et + 128 * 256;                    // [256][256]
    unsigned short* w2nt = w1nt + 256 * 256;                    // [128][256]
    int* cnt  = (int*)(ws + 458752);                            // [NN]  (also fill cursor)
    int* offs = (int*)(ws + 458752 + 400000);                   // [NN+1]
    int* adj  = (int*)(ws + 458752 + 400000 + 400004);          // [2*NE]

    hipMemsetAsync(cnt, 0, (size_t)NN * sizeof(int), stream);

    transpose_cast<<<(384 * 256 + 255) / 256, 256, 0, stream>>>(W1e, w1et, 384, 256);
    transpose_cast<<<(256 * 128 + 255) / 256, 256, 0, stream>>>(W2e, w2et, 256, 128);
    transpose_cast<<<(256 * 256 + 255) / 256, 256, 0, stream>>>(W1n, w1nt, 256, 256);
    transpose_cast<<<(256 * 128 + 255) / 256, 256, 0, stream>>>(W2n, w2nt, 256, 128);

    count_kernel<<<(NE + 255) / 256, 256, 0, stream>>>(esrc, edst, cnt);
    scan_kernel<<<1, 1024, 0, stream>>>(cnt, offs);
    fill_kernel<<<(NE + 255) / 256, 256, 0, stream>>>(esrc, edst, cnt, adj);

    edge_kernel<<<NE / 64, 256, 0, stream>>>(node_rep, edge_attr, esrc, edst,
                                             w1et, b1e, w2et, b2e, edge_out);

    node_kernel<<<(NN + 63) / 64, 256, 0, stream>>>(node_rep, offs, adj, edge_out,
                                                    w1nt, b1n, w2nt, b2n, node_out);
}